// Round 9
// baseline (179.777 us; speedup 1.0000x reference)
//
#include <hip/hip_runtime.h>
#include <math.h>

// Problem constants (from reference setup_inputs): B=4, C=32, H=W=256
#define B_N 4
#define C_N 32
#define H_N 256
#define W_N 256
#define PI_D 3.14159265358979323846
#define LSQ 257   // float2 stride per sequence core-scratch region
#define YROW 34   // float2 stride per row of cols_real output-staging (even -> 16B aligned)

typedef float f32x4 __attribute__((ext_vector_type(4)));

__device__ __forceinline__ float2 cmul(float2 a, float2 b) {
    return make_float2(a.x * b.x - a.y * b.y, a.x * b.y + a.y * b.x);
}
__device__ __forceinline__ float2 f2add(float2 a, float2 b) {
    return make_float2(a.x + b.x, a.y + b.y);
}
__device__ __forceinline__ float2 f2sub(float2 a, float2 b) {
    return make_float2(a.x - b.x, a.y - b.y);
}

// ---------------- per-block chirp/twiddle tables -----------------------------
__device__ __forceinline__ void make_tables(int tid, const float* __restrict__ alpha_p,
                                            float2* c1l, float2* c2l, float2* twl,
                                            float* sscl) {
    if (tid < 256) {
        int j = tid;
        double a = fmin(fmax((double)alpha_p[0], 1e-4), 2.0 - 1e-4);
        double tan_a2 = tan(a * PI_D / 4.0);
        double sin_a  = sin(a * PI_D / 2.0);   // > 0 for a in (0,2)
        double n = (double)(j - 128);
        float sn, cs;

        double u1 = n * n * tan_a2 * (1.0 / 256.0);   // phase = -pi*u1
        u1 -= 2.0 * floor(u1 * 0.5);                  // mod 2
        __sincosf((float)(-PI_D * u1), &sn, &cs);
        c1l[j] = make_float2(cs, sn);

        double u2 = n * n / (256.0 * sin_a);
        u2 -= 2.0 * floor(u2 * 0.5);
        __sincosf((float)(-PI_D * u2), &sn, &cs);
        c2l[j] = make_float2(cs, sn);

        int k1 = j >> 4, t = j & 15;
        __sincosf((float)(-2.0 * PI_D * (double)(t * k1) * (1.0 / 256.0)), &sn, &cs);
        twl[j] = make_float2(cs, sn);

        if (j == 0) *sscl = (float)(1.0 / sqrt(fabs(sin_a) + 1e-12));
    }
}

// ---------------- FFT16 in registers (radix-4 x radix-4) ---------------------
// Input: v[n] natural order. Output: v[4*(k&3) + (k>>2)] = F[k].
template <bool INV>
__device__ __forceinline__ void fft16(float2* v) {
    const float C1 = 0.9238795325112867f, S1 = 0.3826834323650898f;
    const float C2 = 0.7071067811865476f;
    const float2 tw1 = make_float2(C1, INV ? S1 : -S1);
    const float2 tw2 = make_float2(C2, INV ? C2 : -C2);
    const float2 tw3 = make_float2(S1, INV ? C1 : -C1);
    const float2 tw4 = make_float2(0.0f, INV ? 1.0f : -1.0f);
    const float2 tw6 = make_float2(-C2, INV ? C2 : -C2);
    const float2 tw9 = make_float2(-C1, INV ? -S1 : S1);
    float2 u[16];
    #pragma unroll
    for (int n2 = 0; n2 < 4; ++n2) {
        float2 e0 = v[n2], e1 = v[4 + n2], e2 = v[8 + n2], e3 = v[12 + n2];
        float2 t0 = f2add(e0, e2), t1 = f2sub(e0, e2);
        float2 t2 = f2add(e1, e3), t3 = f2sub(e1, e3);
        float2 A0 = f2add(t0, t2);
        float2 A2 = f2sub(t0, t2);
        float2 A1, A3;
        if (!INV) { A1 = make_float2(t1.x + t3.y, t1.y - t3.x);
                    A3 = make_float2(t1.x - t3.y, t1.y + t3.x); }
        else      { A1 = make_float2(t1.x - t3.y, t1.y + t3.x);
                    A3 = make_float2(t1.x + t3.y, t1.y - t3.x); }
        u[n2] = A0;
        if (n2 == 0) { u[4 + n2] = A1;            u[8 + n2] = A2;            u[12 + n2] = A3; }
        if (n2 == 1) { u[4 + n2] = cmul(A1, tw1); u[8 + n2] = cmul(A2, tw2); u[12 + n2] = cmul(A3, tw3); }
        if (n2 == 2) { u[4 + n2] = cmul(A1, tw2); u[8 + n2] = cmul(A2, tw4); u[12 + n2] = cmul(A3, tw6); }
        if (n2 == 3) { u[4 + n2] = cmul(A1, tw3); u[8 + n2] = cmul(A2, tw6); u[12 + n2] = cmul(A3, tw9); }
    }
    #pragma unroll
    for (int k1 = 0; k1 < 4; ++k1) {
        float2 e0 = u[4 * k1], e1 = u[4 * k1 + 1], e2 = u[4 * k1 + 2], e3 = u[4 * k1 + 3];
        float2 t0 = f2add(e0, e2), t1 = f2sub(e0, e2);
        float2 t2 = f2add(e1, e3), t3 = f2sub(e1, e3);
        v[4 * k1 + 0] = f2add(t0, t2);
        v[4 * k1 + 2] = f2sub(t0, t2);
        if (!INV) { v[4 * k1 + 1] = make_float2(t1.x + t3.y, t1.y - t3.x);
                    v[4 * k1 + 3] = make_float2(t1.x - t3.y, t1.y + t3.x); }
        else      { v[4 * k1 + 1] = make_float2(t1.x - t3.y, t1.y + t3.x);
                    v[4 * k1 + 3] = make_float2(t1.x + t3.y, t1.y - t3.x); }
    }
}
#define REG(k) (4 * ((k) & 3) + ((k) >> 2))

// ---------------- FRFT core: 256-pt four-step radix-16, BARRIER-FREE ---------
// Requires: the 16 t-threads of one sequence are contiguous within one wave
// (t = tid&15, seq = tid>>4). All LDS exchange stays inside the wave: LDS ops
// from one wave are program-ordered, so only compiler fences are needed.
// sp: this sequence's 16x16 LDS matrix (XOR swizzle: (r,c) at sp[16r + (c^r)]).
__device__ __forceinline__ void frft_core16(float2* v, float2* __restrict__ sp,
                                            int t,
                                            const float2* __restrict__ c2l,
                                            const float2* __restrict__ twl) {
    fft16<false>(v);  // over n1 -> A[k1] at v[REG(k1)]
    float2 w[16];
    #pragma unroll
    for (int k1 = 0; k1 < 16; ++k1)
        w[k1] = cmul(v[REG(k1)], twl[16 * k1 + t]);   // * W256^{t*k1}
    #pragma unroll
    for (int k1 = 0; k1 < 16; ++k1)
        sp[16 * k1 + (t ^ k1)] = w[k1];               // M[k1][t]
    __builtin_amdgcn_wave_barrier();
    #pragma unroll
    for (int n2 = 0; n2 < 16; ++n2)
        v[n2] = sp[16 * t + (n2 ^ t)];                // M[t][n2]
    fft16<false>(v);  // over n2 -> B[k2] = X[t + 16*k2] at v[REG(k2)]
    #pragma unroll
    for (int k2 = 0; k2 < 16; ++k2)
        w[k2] = cmul(v[REG(k2)], c2l[t + 16 * k2]);   // mid: * c2
    fft16<true>(w);   // over k2 -> C[m2] at w[REG(m2)]
    __builtin_amdgcn_wave_barrier();
    #pragma unroll
    for (int m2 = 0; m2 < 16; ++m2) {
        float2 tw = twl[16 * m2 + t];
        tw.y = -tw.y;                                 // W256^{+t*m2}
        sp[16 * m2 + (t ^ m2)] = cmul(w[REG(m2)], tw);
    }
    __builtin_amdgcn_wave_barrier();
    #pragma unroll
    for (int k1 = 0; k1 < 16; ++k1)
        v[k1] = sp[16 * t + (k1 ^ t)];
    fft16<true>(v);   // over k1 -> z[16*m1 + t] at v[REG(m1)]
}

// ---------------- K1: FRFT along H on REAL input x -> Y ----------------------
// 32 columns per block, 512 threads. Coalesced float4 input staging through
// LDS; barrier-free core (seq = tid>>4 -> quarter-wave sequences); output
// restaged through LDS for coalesced float4 stores (fixes the ~4x HBM write
// amplification of stride-2KB 8B stores).
__global__ __launch_bounds__(512) void frft_cols_real(
        const float* __restrict__ x,
        const float* __restrict__ alpha_p,
        float2* __restrict__ Y) {
    __shared__ float2 s[H_N * YROW];               // 8704 float2 = 69.6 KB (>= 32*LSQ)
    __shared__ float2 c1l[256], c2l[256], twl[256];
    __shared__ float sscl;
    int tid = threadIdx.x;

    int blk = blockIdx.x;
    int w0 = (blk & 7) << 5;                       // 32-col tile
    long long bc = blk >> 3;
    const float* xb = x + (bc << 16) + w0;

    // issue coalesced loads first (latency overlapped by table compute)
    float4 xv[4];
    #pragma unroll
    for (int p = 0; p < 4; ++p) {
        int idx = tid + (p << 9);                  // 0..2047
        int row = idx >> 3, c4 = idx & 7;
        xv[p] = *(const float4*)(xb + row * W_N + (c4 << 2));
    }

    make_tables(tid, alpha_p, c1l, c2l, twl, &sscl);

    // stage tile into LDS (dword view of s): col-region stride 2*LSQ floats
    float* fs = (float*)s;
    #pragma unroll
    for (int p = 0; p < 4; ++p) {
        int idx = tid + (p << 9);
        int row = idx >> 3, c4 = idx & 7;
        fs[(4 * c4 + 0) * (2 * LSQ) + row] = xv[p].x;
        fs[(4 * c4 + 1) * (2 * LSQ) + row] = xv[p].y;
        fs[(4 * c4 + 2) * (2 * LSQ) + row] = xv[p].z;
        fs[(4 * c4 + 3) * (2 * LSQ) + row] = xv[p].w;
    }
    __syncthreads();   // staging + tables visible to all

    int t = tid & 15, seq = tid >> 4;              // quarter-wave sequences
    float xs[16];
    #pragma unroll
    for (int n1 = 0; n1 < 16; ++n1)
        xs[n1] = fs[seq * (2 * LSQ) + 16 * (n1 ^ 8) + t];  // ifftshift
    float scl_v = sscl;
    __builtin_amdgcn_wave_barrier();               // order staging reads vs core writes

    float2 v[16];
    #pragma unroll
    for (int n1 = 0; n1 < 16; ++n1) {
        float2 c = c1l[16 * n1 + t];
        v[n1] = make_float2(xs[n1] * c.x, xs[n1] * c.y);
    }

    frft_core16(v, s + seq * LSQ, t, c2l, twl);

    float sc = scl_v * (1.0f / 256.0f);
    float2 ov[16];
    #pragma unroll
    for (int m1 = 0; m1 < 16; ++m1) {
        float2 o = cmul(v[REG(m1)], c1l[16 * m1 + t]);
        ov[m1] = make_float2(o.x * sc, o.y * sc);
    }
    __syncthreads();   // all cores done before output staging overwrites s

    // output staging: Ys[row][seq], row = final (fftshifted) h index
    #pragma unroll
    for (int m1 = 0; m1 < 16; ++m1)
        s[(16 * (m1 ^ 8) + t) * YROW + seq] = ov[m1];
    __syncthreads();

    // coalesced float4 stores: 16 lanes cover 64 consecutive floats
    int seq2 = tid & 15, rr = tid >> 4;
    float2* Yb = Y + (bc << 16) + w0;
    #pragma unroll
    for (int p = 0; p < 8; ++p) {
        int row = rr + (p << 5);
        f32x4 val = *(f32x4*)&s[row * YROW + 2 * seq2];
        *(f32x4*)(Yb + (long long)row * W_N + 2 * seq2) = val;
    }
}

// ---------------- K2: FRFT along W fused with mag/ang + 1x1 conv -------------
// One block per (b,h): 512 threads = 32 channels x 16 element-groups.
// Barrier-free core; only 2 block barriers (tables, pre-conv). Conv uses
// wave-uniform obase (readfirstlane) -> s_load weights on the scalar pipe.
__device__ __forceinline__ float fast_atan2(float y, float x) {
    float ax = fabsf(x), ay = fabsf(y);
    float mx = fmaxf(ax, ay), mn = fminf(ax, ay);
    float z = mn * __builtin_amdgcn_rcpf(fmaxf(mx, 1e-37f));
    float z2 = z * z;
    float p = fmaf(z2, -0.01172120f, 0.05265332f);
    p = fmaf(z2, p, -0.11643287f);
    p = fmaf(z2, p, 0.19354346f);
    p = fmaf(z2, p, -0.33262347f);
    p = fmaf(z2, p, 0.99997726f);
    p = p * z;
    float r = (ay > ax) ? (1.5707963f - p) : p;
    r = (x < 0.0f) ? (3.14159265f - r) : r;
    return copysignf(r, y);
}

__global__ __launch_bounds__(512) void frft_rows_conv(
        const float2* __restrict__ Y,
        const float* __restrict__ alpha_p,
        const float* __restrict__ wmat, float* __restrict__ out) {
    __shared__ float2 s[32 * LSQ];   // per-channel regions; ends as (mag,ang)
    __shared__ float2 c1l[256], c2l[256], twl[256];
    __shared__ float sscl;
    int tid = threadIdx.x;
    int t = tid & 15, ch = tid >> 4;  // sequence = quarter-wave

    int b = blockIdx.x >> 8, h = blockIdx.x & 255;
    const float2* xr = Y + (((long long)(b * C_N + ch)) << 16) + (h << 8);

    float2 v[16];
    #pragma unroll
    for (int n1 = 0; n1 < 16; ++n1)
        v[n1] = xr[16 * (n1 ^ 8) + t];   // ifftshift along W

    make_tables(tid, alpha_p, c1l, c2l, twl, &sscl);
    __syncthreads();                     // tables ready

    #pragma unroll
    for (int n1 = 0; n1 < 16; ++n1)
        v[n1] = cmul(v[n1], c1l[16 * n1 + t]);

    float2* sp = s + ch * LSQ;
    frft_core16(v, sp, t, c2l, twl);

    // Store (mag, ang/pi) into own region (same-wave WAR with core's reads).
    float sc = sscl * (1.0f / 256.0f);
    __builtin_amdgcn_wave_barrier();
    #pragma unroll
    for (int m1 = 0; m1 < 16; ++m1) {
        float2 o = cmul(v[REG(m1)], c1l[16 * m1 + t]);
        float mg = sc * sqrtf(fmaf(o.x, o.x, o.y * o.y));
        float an = fast_atan2(o.y, o.x) * 0.31830988618f;  // 1/pi
        sp[16 * (m1 ^ 8) + t] = make_float2(mg, an);       // index = final pixel w
    }
    __syncthreads();

    // ---- conv phase: thread (w, half) computes 16 output channels ----
    int w = tid & 255;
    int obase = __builtin_amdgcn_readfirstlane((tid >> 8) << 4);  // 0 or 16
    const float* wrow = wmat + obase * 64;

    float acc[16];
    #pragma unroll
    for (int o = 0; o < 16; ++o) acc[o] = 0.0f;

    #pragma unroll 4
    for (int c = 0; c < C_N; ++c) {
        float2 yv = s[c * LSQ + w];   // (mag, ang)
        #pragma unroll
        for (int o = 0; o < 16; ++o) {
            acc[o] = fmaf(wrow[o * 64 + c], yv.x, acc[o]);
            acc[o] = fmaf(wrow[o * 64 + 32 + c], yv.y, acc[o]);
        }
    }

    float* ob = out + (((long long)(b * C_N + obase)) << 16) + (h << 8) + w;
    #pragma unroll
    for (int o = 0; o < 16; ++o)
        ob[(long long)o << 16] = acc[o];
}

// ---------------- launch -----------------------------------------------------
extern "C" void kernel_launch(void* const* d_in, const int* in_sizes, int n_in,
                              void* d_out, int out_size, void* d_ws, size_t ws_size,
                              hipStream_t stream) {
    const float* x     = (const float*)d_in[0];
    const float* alpha = (const float*)d_in[1];
    const float* wmat  = (const float*)d_in[2];
    float* out = (float*)d_out;

    float2* Y = (float2*)d_ws;   // 64 MiB intermediate (H-pass output)

    // Pass 1: FRFT along H on real input (order commutes with W pass).
    frft_cols_real<<<B_N * C_N * (W_N / 32), 512, 0, stream>>>(x, alpha, Y);

    // Pass 2: FRFT along W + magnitude/phase + 1x1 conv, fused per (b,h).
    frft_rows_conv<<<B_N * H_N, 512, 0, stream>>>(Y, alpha, wmat, out);
}